// Round 7
// baseline (230.699 us; speedup 1.0000x reference)
//
#include <hip/hip_runtime.h>
#include <stdint.h>
#include <stddef.h>

#define L_SEQ 2048
#define NB 4
#define NH 16
#define HDIM 64
#define DMODEL 1024
// 1/sqrt(64) * log2(e): softmax computed in exp2 domain
#define ATT_SCALE_L2E 0.1803368801f

typedef __attribute__((ext_vector_type(4))) float f32x4;
typedef __attribute__((ext_vector_type(16))) float f32x16;
typedef __attribute__((ext_vector_type(8))) __bf16 bf16x8;
typedef __attribute__((ext_vector_type(4))) __bf16 bf16x4;

__device__ __forceinline__ void gload16(const void* g, void* l) {
  __builtin_amdgcn_global_load_lds((const __attribute__((address_space(1))) void*)g,
                                   (__attribute__((address_space(3))) void*)l, 16, 0, 0);
}

// ---------------- prep: x fp32 -> bf16 ----------------
__global__ void k_convert_x(const float* __restrict__ x, __bf16* __restrict__ xb) {
  int i = (blockIdx.x * 256 + threadIdx.x) * 4;
  float4 v = *(const float4*)(x + i);
  bf16x4 o;
  o[0] = (__bf16)v.x; o[1] = (__bf16)v.y; o[2] = (__bf16)v.z; o[3] = (__bf16)v.w;
  *(bf16x4*)(xb + i) = o;
}

// ---------------- prep: W (RxC fp32) -> Wt (CxR bf16) ----------------
__global__ void k_transpose_bf16(const float* __restrict__ W, __bf16* __restrict__ Wt,
                                 int R, int C) {
  __shared__ float t[32][33];
  int c0 = blockIdx.x * 32, r0 = blockIdx.y * 32;
  int tx = threadIdx.x, ty = threadIdx.y;  // 32 x 8
#pragma unroll
  for (int i = 0; i < 32; i += 8)
    t[ty + i][tx] = W[(size_t)(r0 + ty + i) * C + c0 + tx];
  __syncthreads();
#pragma unroll
  for (int i = 0; i < 32; i += 8)
    Wt[(size_t)(c0 + ty + i) * R + r0 + tx] = (__bf16)t[tx][ty + i];
}

// ============ 256-wide GEMM: 3-stage counted-vmcnt pipeline, raw barriers ======
// C = A(Mx1024) * Bt(Nx1024)^T + bias.  BM=256, BN=256 or 128, BK=32, 8 waves.
// LDS: 3 buffers x (A 16KB + B BN*64B). Stage kt+2 while computing kt; one
// vmcnt(ISS)+s_barrier per K-tile (K-tile kt+1 landed; kt+2's ISS loads in
// flight across the barrier). No __syncthreads in the loop (no vmcnt(0) drain).
template <int BN, int EPI>
__global__ __launch_bounds__(512, 2) void k_gemm256(
    const __bf16* __restrict__ A, const __bf16* __restrict__ Bt,
    const float* __restrict__ bias, float* __restrict__ Cf,
    __bf16* __restrict__ Qo, __bf16* __restrict__ Ko, __bf16* __restrict__ Vto,
    int N) {
  constexpr int BUFSZ = 16384 + BN * 64;   // bytes per stage (A + B)
  constexpr int ISS_B = BN / 128;          // 8KB B-issues per K-tile
  constexpr int ISS = 2 + ISS_B;           // gloads per K-tile per wave
  constexpr int NR = BN / 64;              // n-frags per wave
  __shared__ __align__(16) char lds[3 * BUFSZ];

  const int tid = threadIdx.x;
  const int wave = tid >> 6, lane = tid & 63;
  const int wr = wave >> 2, wc = wave & 3;
  const int c16 = lane & 15, g = lane >> 4;
  const int brow = blockIdx.y * 256, bcol = blockIdx.x * BN;

  f32x4 acc[8][NR];
#pragma unroll
  for (int m = 0; m < 8; ++m)
#pragma unroll
    for (int n = 0; n < NR; ++n) acc[m][n] = (f32x4){0.f, 0.f, 0.f, 0.f};

  // staging sources: thread tid covers LDS bytes tid*16 of each 8KB issue:
  // row = tid>>2, col elems = (tid&3)*8
  const __bf16* aSrc = A + (size_t)(brow + (tid >> 2)) * 1024 + (tid & 3) * 8;
  const __bf16* bSrc = Bt + (size_t)(bcol + (tid >> 2)) * 1024 + (tid & 3) * 8;

#define STAGE(kt, sel) do {                                                  \
    char* lb_ = lds + (sel) * BUFSZ + wave * 1024;                           \
    gload16(aSrc + (kt) * 32, lb_);                                          \
    gload16(aSrc + (kt) * 32 + (size_t)128 * 1024, lb_ + 8192);              \
    gload16(bSrc + (kt) * 32, lb_ + 16384);                                  \
    if (ISS_B == 2) gload16(bSrc + (kt) * 32 + (size_t)128 * 1024,           \
                            lb_ + 16384 + 8192);                             \
  } while (0)

  STAGE(0, 0);
  STAGE(1, 1);
  asm volatile("s_waitcnt vmcnt(%0)" ::"n"(ISS) : "memory");  // kt0 landed
  asm volatile("s_barrier" ::: "memory");

  int bs = 0;  // buffer holding current kt
  for (int kt = 0; kt < 32; ++kt) {
    if (kt < 30) {
      int sel = (bs == 0) ? 2 : bs - 1;  // (bs+2)%3 == buffer of kt-1 (dead)
      STAGE(kt + 2, sel);
    }
    const char* bufA = lds + bs * BUFSZ;
    const char* bufB = bufA + 16384;
    bf16x8 af[8], bfr[NR];
#pragma unroll
    for (int m = 0; m < 8; ++m)
      af[m] = *(const bf16x8*)(bufA + (wr * 128 + m * 16 + c16) * 64 + g * 16);
#pragma unroll
    for (int n = 0; n < NR; ++n)
      bfr[n] = *(const bf16x8*)(bufB + (wc * (BN / 4) + n * 16 + c16) * 64 + g * 16);
#pragma unroll
    for (int m = 0; m < 8; ++m)
#pragma unroll
      for (int n = 0; n < NR; ++n)
        acc[m][n] = __builtin_amdgcn_mfma_f32_16x16x32_bf16(af[m], bfr[n], acc[m][n], 0, 0, 0);
    if (kt < 30)
      asm volatile("s_waitcnt vmcnt(%0)" ::"n"(ISS) : "memory");  // kt+1 landed
    else if (kt == 30)
      asm volatile("s_waitcnt vmcnt(0)" ::: "memory");            // kt31 landed
    if (kt < 31) asm volatile("s_barrier" ::: "memory");
    bs = (bs == 2) ? 0 : bs + 1;
  }
#undef STAGE

#pragma unroll
  for (int m = 0; m < 8; ++m) {
#pragma unroll
    for (int n = 0; n < NR; ++n) {
      int gcol = bcol + wc * (BN / 4) + n * 16 + c16;
      float bv = bias[gcol];
#pragma unroll
      for (int r = 0; r < 4; ++r) {
        int grow = brow + wr * 128 + m * 16 + g * 4 + r;
        float v = acc[m][n][r] + bv;
        if (EPI == 0) {
          int which = gcol >> 10, hh = (gcol >> 6) & 15, d = gcol & 63;
          int b = grow >> 11, l = grow & 2047;
          size_t bh = (size_t)b * NH + hh;
          if (which == 0)
            Qo[(bh * L_SEQ + l) * HDIM + d] = (__bf16)(v * ATT_SCALE_L2E);
          else if (which == 1)
            Ko[(bh * L_SEQ + l) * HDIM + d] = (__bf16)v;
          else
            Vto[(bh * HDIM + d) * L_SEQ + l] = (__bf16)v;
        } else {
          Cf[(size_t)grow * N + gcol] = v;
        }
      }
    }
  }
}

// ---------------- helpers ----------------
__device__ __forceinline__ float fexp2(float x) {
  float r;
  asm("v_exp_f32 %0, %1" : "=v"(r) : "v"(x));
  return r;
}
__device__ __forceinline__ int cvtpk(float a, float b) {
  int r;
  asm("v_cvt_pk_bf16_f32 %0, %1, %2" : "=v"(r) : "v"(a), "v"(b));
  return r;
}
// only safe when a,b are DISTINCT values (distinct registers) — round-4 lesson
__device__ __forceinline__ void pswap(int& a, int& b) {
  asm("v_permlane32_swap_b32 %0, %1" : "+v"(a), "+v"(b));
}
// Build PV A-fragment from 8 in-lane P values (verified rounds 1-3)
__device__ __forceinline__ bf16x8 make_pa(float p0, float p1, float p2, float p3,
                                          float p4, float p5, float p6, float p7) {
  int a0 = cvtpk(p0, p1);
  int a1 = cvtpk(p2, p3);
  int b0 = cvtpk(p4, p5);
  int b1 = cvtpk(p6, p7);
  pswap(a0, b0);
  pswap(a1, b1);
  union { int i[4]; bf16x8 v; } u;
  u.i[0] = a0; u.i[1] = a1; u.i[2] = b0; u.i[3] = b1;
  return u.v;
}

// ---------------- flash attention: LDS-staged KV, 2-phase pipeline ----------------
__global__ __launch_bounds__(256, 4) void k_attn(
    const __bf16* __restrict__ Q, const __bf16* __restrict__ K,
    const __bf16* __restrict__ Vt, __bf16* __restrict__ O) {
  __shared__ char kv_lds[32768];

  const int blk = blockIdx.x;                    // 0..1023
  const int idx = (blk & 7) * 128 + (blk >> 3);  // bijective XCD swizzle
  const int bh = idx >> 4;
  const int qt = idx & 15;
  const int tid = threadIdx.x;
  const int wave = tid >> 6, lane = tid & 63;
  const int r31 = lane & 31, hi = lane >> 5;
  const int swz = (r31 & 7) << 4;
  const int qw = qt * 128 + wave * 32;
  const __bf16* Qb = Q + (size_t)bh * L_SEQ * HDIM;
  const char* Kc = (const char*)(K + (size_t)bh * L_SEQ * HDIM);
  const char* Vc = (const char*)(Vt + (size_t)bh * HDIM * L_SEQ);

  const char* gK0; const char* gK1; const char* gV0; const char* gV1;
  {
    int Y0 = tid * 16, Y1 = 4096 + tid * 16;
    int r0 = Y0 >> 7, r1 = Y1 >> 7;
    int c0 = (Y0 & 127) ^ ((r0 & 7) << 4);
    int c1 = (Y1 & 127) ^ ((r1 & 7) << 4);
    gK0 = Kc + r0 * 128 + c0;
    gK1 = Kc + r1 * 128 + c1;
    gV0 = Vc + (size_t)r0 * 4096 + c0;
    gV1 = Vc + (size_t)r1 * 4096 + c1;
  }

  bf16x8 qf[4];
#pragma unroll
  for (int kc = 0; kc < 4; ++kc)
    qf[kc] = *(const bf16x8*)(Qb + (size_t)(qw + r31) * HDIM + kc * 16 + hi * 8);

  f32x16 o0 = {}, o1 = {};
  float m = -1e30f, l = 0.f;

#define STAGEA(buf, kvb) do {                                                    \
    char* lb_ = kv_lds + (buf) * 16384 + wave * 1024;                            \
    gload16(gK0 + (size_t)(kvb) * 128, lb_);                                     \
    gload16(gK1 + (size_t)(kvb) * 128, lb_ + 4096);                              \
    gload16(gV0 + (kvb) * 2, lb_ + 8192);                                        \
    gload16(gV1 + (kvb) * 2, lb_ + 8192 + 4096);                                 \
  } while (0)

#define BODYL(t, bufo) do {                                                        \
    const char* kb_ = kv_lds + (bufo) + ((t) * 32 + r31) * 128;                    \
    bf16x8 kf0 = *(const bf16x8*)(kb_ + ((hi * 16) ^ swz));                        \
    bf16x8 kf1 = *(const bf16x8*)(kb_ + ((32 + hi * 16) ^ swz));                   \
    bf16x8 kf2 = *(const bf16x8*)(kb_ + ((64 + hi * 16) ^ swz));                   \
    bf16x8 kf3 = *(const bf16x8*)(kb_ + ((96 + hi * 16) ^ swz));                   \
    f32x16 s = {};                                                                 \
    s = __builtin_amdgcn_mfma_f32_32x32x16_bf16(kf0, qf[0], s, 0, 0, 0);           \
    s = __builtin_amdgcn_mfma_f32_32x32x16_bf16(kf1, qf[1], s, 0, 0, 0);           \
    s = __builtin_amdgcn_mfma_f32_32x32x16_bf16(kf2, qf[2], s, 0, 0, 0);           \
    s = __builtin_amdgcn_mfma_f32_32x32x16_bf16(kf3, qf[3], s, 0, 0, 0);           \
    float t8[8];                                                                   \
    _Pragma("unroll") for (int i = 0; i < 8; ++i) t8[i] = fmaxf(s[i], s[i + 8]);   \
    _Pragma("unroll") for (int i = 0; i < 4; ++i) t8[i] = fmaxf(t8[i], t8[i + 4]); \
    float mx = fmaxf(fmaxf(t8[0], t8[1]), fmaxf(t8[2], t8[3]));                    \
    mx = fmaxf(mx, __shfl_xor(mx, 32, 64));                                        \
    if (__any(mx > m + 12.f)) {                                                    \
      float mnew = fmaxf(m, mx);                                                   \
      float corr = fexp2(m - mnew);                                                \
      l *= corr;                                                                   \
      _Pragma("unroll") for (int r = 0; r < 16; ++r) {                             \
        float cr = __shfl(corr, (r & 3) + 8 * (r >> 2) + 4 * hi, 64);              \
        o0[r] *= cr; o1[r] *= cr;                                                  \
      }                                                                            \
      m = mnew;                                                                    \
    }                                                                              \
    _Pragma("unroll") for (int i = 0; i < 16; ++i) s[i] = fexp2(s[i] - m);         \
    float a8[8];                                                                   \
    _Pragma("unroll") for (int i = 0; i < 8; ++i) a8[i] = s[i] + s[i + 8];         \
    _Pragma("unroll") for (int i = 0; i < 4; ++i) a8[i] += a8[i + 4];              \
    l += (a8[0] + a8[1]) + (a8[2] + a8[3]);                                        \
    const char* vb_ = kv_lds + (bufo) + 8192 + r31 * 128;                          \
    bf16x8 pa = make_pa(s[0], s[1], s[2], s[3], s[4], s[5], s[6], s[7]);           \
    o0 = __builtin_amdgcn_mfma_f32_32x32x16_bf16(                                  \
        pa, *(const bf16x8*)(vb_ + (((t) * 64 + hi * 16) ^ swz)), o0, 0, 0, 0);    \
    o1 = __builtin_amdgcn_mfma_f32_32x32x16_bf16(                                  \
        pa, *(const bf16x8*)(vb_ + 4096 + (((t) * 64 + hi * 16) ^ swz)), o1, 0, 0, 0); \
    pa = make_pa(s[8], s[9], s[10], s[11], s[12], s[13], s[14], s[15]);            \
    o0 = __builtin_amdgcn_mfma_f32_32x32x16_bf16(                                  \
        pa, *(const bf16x8*)(vb_ + (((t) * 64 + 32 + hi * 16) ^ swz)), o0, 0, 0, 0); \
    o1 = __builtin_amdgcn_mfma_f32_32x32x16_bf16(                                  \
        pa, *(const bf16x8*)(vb_ + 4096 + (((t) * 64 + 32 + hi * 16) ^ swz)), o1, 0, 0, 0); \
  } while (0)

  int cur = 0;
  STAGEA(0, 0);
  __syncthreads();
  for (int t = 0; t < L_SEQ / 64; ++t) {
    if (t < L_SEQ / 64 - 1) STAGEA(cur ^ 1, (t + 1) * 64);
    BODYL(0, cur * 16384);
    BODYL(1, cur * 16384);
    __syncthreads();
    cur ^= 1;
  }
#undef STAGEA
#undef BODYL

  l += __shfl_xor(l, 32, 64);
  const int b = bh >> 4, h = bh & 15;
  float linv = 1.f / l;
#pragma unroll
  for (int r = 0; r < 16; ++r) {
    int ql = (r & 3) + 8 * (r >> 2) + 4 * hi;
    float li = __shfl(linv, ql, 64);
    size_t base = ((size_t)b * L_SEQ + qw + ql) * DMODEL + h * 64 + r31;
    O[base] = (__bf16)(o0[r] * li);
    O[base + 32] = (__bf16)(o1[r] * li);
  }
}

extern "C" void kernel_launch(void* const* d_in, const int* in_sizes, int n_in,
                              void* d_out, int out_size, void* d_ws, size_t ws_size,
                              hipStream_t stream) {
  const float* x = (const float*)d_in[0];
  const float* Wqkv = (const float*)d_in[1];
  const float* bqkv = (const float*)d_in[2];
  const float* Wout = (const float*)d_in[3];
  const float* bout = (const float*)d_in[4];
  float* out = (float*)d_out;

  char* ws = (char*)d_ws;
  __bf16* Xb    = (__bf16*)(ws + 0);
  __bf16* Wqkvt = (__bf16*)(ws + 16777216);
  __bf16* Woutt = (__bf16*)(ws + 23068672);
  __bf16* Qb    = (__bf16*)(ws + 25165824);
  __bf16* Kb    = (__bf16*)(ws + 41943040);
  __bf16* Vtb   = (__bf16*)(ws + 58720256);
  __bf16* Ob    = (__bf16*)(ws + 0);  // reuse Xb region after GEMM1

  k_convert_x<<<8192, 256, 0, stream>>>(x, Xb);
  k_transpose_bf16<<<dim3(96, 32), dim3(32, 8), 0, stream>>>(Wqkv, Wqkvt, 1024, 3072);
  k_transpose_bf16<<<dim3(32, 32), dim3(32, 8), 0, stream>>>(Wout, Woutt, 1024, 1024);
  // QKV projection: M=8192, N=3072 (256x256 tiles, 384 blocks)
  k_gemm256<256, 0><<<dim3(12, 32), 512, 0, stream>>>(Xb, Wqkvt, bqkv, nullptr,
                                                      Qb, Kb, Vtb, 3072);
  k_attn<<<dim3(1024), 256, 0, stream>>>(Qb, Kb, Vtb, Ob);
  // output projection: M=8192, N=1024 (256x128 tiles, 256 blocks = full chip)
  k_gemm256<128, 1><<<dim3(8, 32), 512, 0, stream>>>(Ob, Woutt, bout, out,
                                                     nullptr, nullptr, nullptr, 1024);
}

// Round 8
// 228.945 us; speedup vs baseline: 1.0077x; 1.0077x over previous
//
#include <hip/hip_runtime.h>
#include <stdint.h>
#include <stddef.h>

#define L_SEQ 2048
#define NB 4
#define NH 16
#define HDIM 64
#define DMODEL 1024
// 1/sqrt(64) * log2(e): softmax computed in exp2 domain
#define ATT_SCALE_L2E 0.1803368801f

typedef __attribute__((ext_vector_type(4))) float f32x4;
typedef __attribute__((ext_vector_type(16))) float f32x16;
typedef __attribute__((ext_vector_type(8))) __bf16 bf16x8;
typedef __attribute__((ext_vector_type(4))) __bf16 bf16x4;

__device__ __forceinline__ void gload16(const void* g, void* l) {
  __builtin_amdgcn_global_load_lds((const __attribute__((address_space(1))) void*)g,
                                   (__attribute__((address_space(3))) void*)l, 16, 0, 0);
}

// ---------------- prep: x fp32 -> bf16 ----------------
__global__ void k_convert_x(const float* __restrict__ x, __bf16* __restrict__ xb) {
  int i = (blockIdx.x * 256 + threadIdx.x) * 4;
  float4 v = *(const float4*)(x + i);
  bf16x4 o;
  o[0] = (__bf16)v.x; o[1] = (__bf16)v.y; o[2] = (__bf16)v.z; o[3] = (__bf16)v.w;
  *(bf16x4*)(xb + i) = o;
}

// ---------------- prep: W (RxC fp32) -> Wt (CxR bf16) ----------------
__global__ void k_transpose_bf16(const float* __restrict__ W, __bf16* __restrict__ Wt,
                                 int R, int C) {
  __shared__ float t[32][33];
  int c0 = blockIdx.x * 32, r0 = blockIdx.y * 32;
  int tx = threadIdx.x, ty = threadIdx.y;  // 32 x 8
#pragma unroll
  for (int i = 0; i < 32; i += 8)
    t[ty + i][tx] = W[(size_t)(r0 + ty + i) * C + c0 + tx];
  __syncthreads();
#pragma unroll
  for (int i = 0; i < 32; i += 8)
    Wt[(size_t)(c0 + ty + i) * R + r0 + tx] = (__bf16)t[tx][ty + i];
}

// ============ 256-wide GEMM: 3-stage counted-vmcnt pipeline + T2 swizzle =======
// C = A(Mx1024) * Bt(Nx1024)^T + bias.  BM=256, BN=256 or 128, BK=32, 8 waves.
// LDS image is XOR-swizzled: byte col' = col ^ (((row>>1)&3)<<4), achieved with
// linear global_load_lds dest + pre-XOR'd GLOBAL source (rule 21), and the same
// XOR on every ds_read -> conflict-free b128 fragment reads (was 4.7M conflicts).
template <int BN, int EPI>
__global__ __launch_bounds__(512, 2) void k_gemm256(
    const __bf16* __restrict__ A, const __bf16* __restrict__ Bt,
    const float* __restrict__ bias, float* __restrict__ Cf,
    __bf16* __restrict__ Qo, __bf16* __restrict__ Ko, __bf16* __restrict__ Vto,
    int N) {
  constexpr int BUFSZ = 16384 + BN * 64;   // bytes per stage (A + B)
  constexpr int ISS_B = BN / 128;          // 8KB B-issues per K-tile
  constexpr int ISS = 2 + ISS_B;           // gloads per K-tile per wave
  constexpr int NR = BN / 64;              // n-frags per wave
  __shared__ __align__(16) char lds[3 * BUFSZ];

  const int tid = threadIdx.x;
  const int wave = tid >> 6, lane = tid & 63;
  const int wr = wave >> 2, wc = wave & 3;
  const int c16 = lane & 15, g = lane >> 4;
  const int brow = blockIdx.y * 256, bcol = blockIdx.x * BN;
  const int fx = ((c16 >> 1) & 3) << 4;    // ds_read byte-XOR (row dep -> c16 dep)

  f32x4 acc[8][NR];
#pragma unroll
  for (int m = 0; m < 8; ++m)
#pragma unroll
    for (int n = 0; n < NR; ++n) acc[m][n] = (f32x4){0.f, 0.f, 0.f, 0.f};

  // staging sources: thread tid covers LDS bytes tid*16 of each 8KB issue
  // (row = tid>>2, col' bytes = (tid&3)*16); source col = col' ^ f(row),
  // f(row) elems = ((row>>1)&3)<<3 = ((tid>>3)&3)<<3.  Involution; kt*32 adds
  // multiples of 32 elems so the XOR (within 32 elems) never carries.
  const int scol = ((tid & 3) * 8) ^ (((tid >> 3) & 3) << 3);
  const __bf16* aSrc = A + (size_t)(brow + (tid >> 2)) * 1024 + scol;
  const __bf16* bSrc = Bt + (size_t)(bcol + (tid >> 2)) * 1024 + scol;

#define STAGE(kt, sel) do {                                                  \
    char* lb_ = lds + (sel) * BUFSZ + wave * 1024;                           \
    gload16(aSrc + (kt) * 32, lb_);                                          \
    gload16(aSrc + (kt) * 32 + (size_t)128 * 1024, lb_ + 8192);              \
    gload16(bSrc + (kt) * 32, lb_ + 16384);                                  \
    if (ISS_B == 2) gload16(bSrc + (kt) * 32 + (size_t)128 * 1024,           \
                            lb_ + 16384 + 8192);                             \
  } while (0)

  STAGE(0, 0);
  STAGE(1, 1);
  asm volatile("s_waitcnt vmcnt(%0)" ::"n"(ISS) : "memory");  // kt0 landed
  asm volatile("s_barrier" ::: "memory");

  int bs = 0;  // buffer holding current kt
  for (int kt = 0; kt < 32; ++kt) {
    if (kt < 30) {
      int sel = (bs == 0) ? 2 : bs - 1;  // buffer of kt-1 (dead, barrier-safe)
      STAGE(kt + 2, sel);
    }
    const char* bufA = lds + bs * BUFSZ;
    const char* bufB = bufA + 16384;
    bf16x8 af[8], bfr[NR];
#pragma unroll
    for (int m = 0; m < 8; ++m)
      af[m] = *(const bf16x8*)(bufA + (wr * 128 + m * 16 + c16) * 64 + ((g * 16) ^ fx));
#pragma unroll
    for (int n = 0; n < NR; ++n)
      bfr[n] = *(const bf16x8*)(bufB + (wc * (BN / 4) + n * 16 + c16) * 64 + ((g * 16) ^ fx));
#pragma unroll
    for (int m = 0; m < 8; ++m)
#pragma unroll
      for (int n = 0; n < NR; ++n)
        acc[m][n] = __builtin_amdgcn_mfma_f32_16x16x32_bf16(af[m], bfr[n], acc[m][n], 0, 0, 0);
    if (kt < 30)
      asm volatile("s_waitcnt vmcnt(%0)" ::"n"(ISS) : "memory");  // kt+1 landed
    else if (kt == 30)
      asm volatile("s_waitcnt vmcnt(0)" ::: "memory");            // kt31 landed
    if (kt < 31) asm volatile("s_barrier" ::: "memory");
    bs = (bs == 2) ? 0 : bs + 1;
  }
#undef STAGE

#pragma unroll
  for (int m = 0; m < 8; ++m) {
#pragma unroll
    for (int n = 0; n < NR; ++n) {
      int gcol = bcol + wc * (BN / 4) + n * 16 + c16;
      float bv = bias[gcol];
#pragma unroll
      for (int r = 0; r < 4; ++r) {
        int grow = brow + wr * 128 + m * 16 + g * 4 + r;
        float v = acc[m][n][r] + bv;
        if (EPI == 0) {
          int which = gcol >> 10, hh = (gcol >> 6) & 15, d = gcol & 63;
          int b = grow >> 11, l = grow & 2047;
          size_t bh = (size_t)b * NH + hh;
          if (which == 0)
            Qo[(bh * L_SEQ + l) * HDIM + d] = (__bf16)(v * ATT_SCALE_L2E);
          else if (which == 1)
            Ko[(bh * L_SEQ + l) * HDIM + d] = (__bf16)v;
          else
            Vto[(bh * HDIM + d) * L_SEQ + l] = (__bf16)v;
        } else {
          Cf[(size_t)grow * N + gcol] = v;
        }
      }
    }
  }
}

// ---------------- helpers ----------------
__device__ __forceinline__ float fexp2(float x) {
  float r;
  asm("v_exp_f32 %0, %1" : "=v"(r) : "v"(x));
  return r;
}
__device__ __forceinline__ int cvtpk(float a, float b) {
  int r;
  asm("v_cvt_pk_bf16_f32 %0, %1, %2" : "=v"(r) : "v"(a), "v"(b));
  return r;
}
// only safe when a,b are DISTINCT values (distinct registers) — round-4 lesson
__device__ __forceinline__ void pswap(int& a, int& b) {
  asm("v_permlane32_swap_b32 %0, %1" : "+v"(a), "+v"(b));
}
// Build PV A-fragment from 8 in-lane P values (verified rounds 1-3)
__device__ __forceinline__ bf16x8 make_pa(float p0, float p1, float p2, float p3,
                                          float p4, float p5, float p6, float p7) {
  int a0 = cvtpk(p0, p1);
  int a1 = cvtpk(p2, p3);
  int b0 = cvtpk(p4, p5);
  int b1 = cvtpk(p6, p7);
  pswap(a0, b0);
  pswap(a1, b1);
  union { int i[4]; bf16x8 v; } u;
  u.i[0] = a0; u.i[1] = a1; u.i[2] = b0; u.i[3] = b1;
  return u.v;
}

// ---------------- flash attention: LDS-staged KV, 2-phase pipeline ----------------
__global__ __launch_bounds__(256, 4) void k_attn(
    const __bf16* __restrict__ Q, const __bf16* __restrict__ K,
    const __bf16* __restrict__ Vt, __bf16* __restrict__ O) {
  __shared__ char kv_lds[32768];

  const int blk = blockIdx.x;                    // 0..1023
  const int idx = (blk & 7) * 128 + (blk >> 3);  // bijective XCD swizzle
  const int bh = idx >> 4;
  const int qt = idx & 15;
  const int tid = threadIdx.x;
  const int wave = tid >> 6, lane = tid & 63;
  const int r31 = lane & 31, hi = lane >> 5;
  const int swz = (r31 & 7) << 4;
  const int qw = qt * 128 + wave * 32;
  const __bf16* Qb = Q + (size_t)bh * L_SEQ * HDIM;
  const char* Kc = (const char*)(K + (size_t)bh * L_SEQ * HDIM);
  const char* Vc = (const char*)(Vt + (size_t)bh * HDIM * L_SEQ);

  const char* gK0; const char* gK1; const char* gV0; const char* gV1;
  {
    int Y0 = tid * 16, Y1 = 4096 + tid * 16;
    int r0 = Y0 >> 7, r1 = Y1 >> 7;
    int c0 = (Y0 & 127) ^ ((r0 & 7) << 4);
    int c1 = (Y1 & 127) ^ ((r1 & 7) << 4);
    gK0 = Kc + r0 * 128 + c0;
    gK1 = Kc + r1 * 128 + c1;
    gV0 = Vc + (size_t)r0 * 4096 + c0;
    gV1 = Vc + (size_t)r1 * 4096 + c1;
  }

  bf16x8 qf[4];
#pragma unroll
  for (int kc = 0; kc < 4; ++kc)
    qf[kc] = *(const bf16x8*)(Qb + (size_t)(qw + r31) * HDIM + kc * 16 + hi * 8);

  f32x16 o0 = {}, o1 = {};
  float m = -1e30f, l = 0.f;

#define STAGEA(buf, kvb) do {                                                    \
    char* lb_ = kv_lds + (buf) * 16384 + wave * 1024;                            \
    gload16(gK0 + (size_t)(kvb) * 128, lb_);                                     \
    gload16(gK1 + (size_t)(kvb) * 128, lb_ + 4096);                              \
    gload16(gV0 + (kvb) * 2, lb_ + 8192);                                        \
    gload16(gV1 + (kvb) * 2, lb_ + 8192 + 4096);                                 \
  } while (0)

#define BODYL(t, bufo) do {                                                        \
    const char* kb_ = kv_lds + (bufo) + ((t) * 32 + r31) * 128;                    \
    bf16x8 kf0 = *(const bf16x8*)(kb_ + ((hi * 16) ^ swz));                        \
    bf16x8 kf1 = *(const bf16x8*)(kb_ + ((32 + hi * 16) ^ swz));                   \
    bf16x8 kf2 = *(const bf16x8*)(kb_ + ((64 + hi * 16) ^ swz));                   \
    bf16x8 kf3 = *(const bf16x8*)(kb_ + ((96 + hi * 16) ^ swz));                   \
    f32x16 s = {};                                                                 \
    s = __builtin_amdgcn_mfma_f32_32x32x16_bf16(kf0, qf[0], s, 0, 0, 0);           \
    s = __builtin_amdgcn_mfma_f32_32x32x16_bf16(kf1, qf[1], s, 0, 0, 0);           \
    s = __builtin_amdgcn_mfma_f32_32x32x16_bf16(kf2, qf[2], s, 0, 0, 0);           \
    s = __builtin_amdgcn_mfma_f32_32x32x16_bf16(kf3, qf[3], s, 0, 0, 0);           \
    float t8[8];                                                                   \
    _Pragma("unroll") for (int i = 0; i < 8; ++i) t8[i] = fmaxf(s[i], s[i + 8]);   \
    _Pragma("unroll") for (int i = 0; i < 4; ++i) t8[i] = fmaxf(t8[i], t8[i + 4]); \
    float mx = fmaxf(fmaxf(t8[0], t8[1]), fmaxf(t8[2], t8[3]));                    \
    mx = fmaxf(mx, __shfl_xor(mx, 32, 64));                                        \
    if (__any(mx > m + 12.f)) {                                                    \
      float mnew = fmaxf(m, mx);                                                   \
      float corr = fexp2(m - mnew);                                                \
      l *= corr;                                                                   \
      _Pragma("unroll") for (int r = 0; r < 16; ++r) {                             \
        float cr = __shfl(corr, (r & 3) + 8 * (r >> 2) + 4 * hi, 64);              \
        o0[r] *= cr; o1[r] *= cr;                                                  \
      }                                                                            \
      m = mnew;                                                                    \
    }                                                                              \
    _Pragma("unroll") for (int i = 0; i < 16; ++i) s[i] = fexp2(s[i] - m);         \
    float a8[8];                                                                   \
    _Pragma("unroll") for (int i = 0; i < 8; ++i) a8[i] = s[i] + s[i + 8];         \
    _Pragma("unroll") for (int i = 0; i < 4; ++i) a8[i] += a8[i + 4];              \
    l += (a8[0] + a8[1]) + (a8[2] + a8[3]);                                        \
    const char* vb_ = kv_lds + (bufo) + 8192 + r31 * 128;                          \
    bf16x8 pa = make_pa(s[0], s[1], s[2], s[3], s[4], s[5], s[6], s[7]);           \
    o0 = __builtin_amdgcn_mfma_f32_32x32x16_bf16(                                  \
        pa, *(const bf16x8*)(vb_ + (((t) * 64 + hi * 16) ^ swz)), o0, 0, 0, 0);    \
    o1 = __builtin_amdgcn_mfma_f32_32x32x16_bf16(                                  \
        pa, *(const bf16x8*)(vb_ + 4096 + (((t) * 64 + hi * 16) ^ swz)), o1, 0, 0, 0); \
    pa = make_pa(s[8], s[9], s[10], s[11], s[12], s[13], s[14], s[15]);            \
    o0 = __builtin_amdgcn_mfma_f32_32x32x16_bf16(                                  \
        pa, *(const bf16x8*)(vb_ + (((t) * 64 + 32 + hi * 16) ^ swz)), o0, 0, 0, 0); \
    o1 = __builtin_amdgcn_mfma_f32_32x32x16_bf16(                                  \
        pa, *(const bf16x8*)(vb_ + 4096 + (((t) * 64 + 32 + hi * 16) ^ swz)), o1, 0, 0, 0); \
  } while (0)

  int cur = 0;
  STAGEA(0, 0);
  __syncthreads();
  for (int t = 0; t < L_SEQ / 64; ++t) {
    if (t < L_SEQ / 64 - 1) STAGEA(cur ^ 1, (t + 1) * 64);
    BODYL(0, cur * 16384);
    BODYL(1, cur * 16384);
    __syncthreads();
    cur ^= 1;
  }
#undef STAGEA
#undef BODYL

  l += __shfl_xor(l, 32, 64);
  const int b = bh >> 4, h = bh & 15;
  float linv = 1.f / l;
#pragma unroll
  for (int r = 0; r < 16; ++r) {
    int ql = (r & 3) + 8 * (r >> 2) + 4 * hi;
    float li = __shfl(linv, ql, 64);
    size_t base = ((size_t)b * L_SEQ + qw + ql) * DMODEL + h * 64 + r31;
    O[base] = (__bf16)(o0[r] * li);
    O[base + 32] = (__bf16)(o1[r] * li);
  }
}

extern "C" void kernel_launch(void* const* d_in, const int* in_sizes, int n_in,
                              void* d_out, int out_size, void* d_ws, size_t ws_size,
                              hipStream_t stream) {
  const float* x = (const float*)d_in[0];
  const float* Wqkv = (const float*)d_in[1];
  const float* bqkv = (const float*)d_in[2];
  const float* Wout = (const float*)d_in[3];
  const float* bout = (const float*)d_in[4];
  float* out = (float*)d_out;

  char* ws = (char*)d_ws;
  __bf16* Xb    = (__bf16*)(ws + 0);
  __bf16* Wqkvt = (__bf16*)(ws + 16777216);
  __bf16* Woutt = (__bf16*)(ws + 23068672);
  __bf16* Qb    = (__bf16*)(ws + 25165824);
  __bf16* Kb    = (__bf16*)(ws + 41943040);
  __bf16* Vtb   = (__bf16*)(ws + 58720256);
  __bf16* Ob    = (__bf16*)(ws + 0);  // reuse Xb region after GEMM1

  k_convert_x<<<8192, 256, 0, stream>>>(x, Xb);
  k_transpose_bf16<<<dim3(96, 32), dim3(32, 8), 0, stream>>>(Wqkv, Wqkvt, 1024, 3072);
  k_transpose_bf16<<<dim3(32, 32), dim3(32, 8), 0, stream>>>(Wout, Woutt, 1024, 1024);
  // QKV projection: M=8192, N=3072 (256x256 tiles, 384 blocks)
  k_gemm256<256, 0><<<dim3(12, 32), 512, 0, stream>>>(Xb, Wqkvt, bqkv, nullptr,
                                                      Qb, Kb, Vtb, 3072);
  k_attn<<<dim3(1024), 256, 0, stream>>>(Qb, Kb, Vtb, Ob);
  // output projection: M=8192, N=1024 (256x128 tiles, 256 blocks = full chip)
  k_gemm256<128, 1><<<dim3(8, 32), 512, 0, stream>>>(Ob, Woutt, bout, out,
                                                     nullptr, nullptr, nullptr, 1024);
}